// Round 13
// baseline (212.560 us; speedup 1.0000x reference)
//
#include <hip/hip_runtime.h>

// EdgeConv with KNN graph: B=8, N=4096, D=3, E=64, K=32.
// R12 post-mortem: grid triple (768/1024/2048 blocks) => 1024x32 is the
// sweet spot (staging amortization vs tail). R10 body is the reference.
// R13 changes (on R10 base):
//  1) FUSED threshold-search + compaction: the compaction scan's ballot
//     popcount accumulator IS cnt_lt(H). Run it optimistically with the
//     seeded H (r=0: sampled 33rd lane-min => count>=32 mod ties; r>0:
//     carried H); accept if base in [32,64], else adjust H (gallop/bisect,
//     counts monotone) and rescan. Common case: ONE 64-slot scan replaces
//     ~2.5 probe scans + 1 compaction scan (~200 VALU/pt saved).
//     Correctness identical: accepted pass has a complete pool, 32<=|pool|
//     <=64; u16 monotone-truncation superset + exact-fp32 partial bitonic
//     (lower-index tie-break == jax.lax.top_k) unchanged from R6-R10.
//  2) planes merged into s_pl[3][NPTS]: 3 sweep ds_reads share one address
//     register via folded immediate offsets (16384/32768 < 64KB DS field).
// Everything else R10-proven: 48KB+2KB LDS -> 3 blocks/CU (24 waves),
// in-sweep sq_j with BIT-IDENTICAL packed fmaf chain, pk[32] u16 keys,
// ballot+mbcnt compaction, readlane epilogue.
// SPILL DISCIPLINE (R2/R3): every loop touching pk[] FULLY unrolled;
// (512,6) 85-VGPR budget, peak live ~75. TRIPWIRE: FETCH>4MB.

#define NPTS 4096
#define KNN  32

#define WFENCE() __asm__ volatile("s_waitcnt lgkmcnt(0)" ::: "memory")

typedef unsigned short u16x2 __attribute__((ext_vector_type(2)));
typedef float          f32x2 __attribute__((ext_vector_type(2)));

__device__ __forceinline__ unsigned lane_prefix(unsigned long long m) {
    return __builtin_amdgcn_mbcnt_hi((unsigned)(m >> 32),
           __builtin_amdgcn_mbcnt_lo((unsigned)m, 0u));
}
__device__ __forceinline__ unsigned pk_min_u16(unsigned a, unsigned b) {
    return __builtin_bit_cast(unsigned, __builtin_elementwise_min(
        __builtin_bit_cast(u16x2, a), __builtin_bit_cast(u16x2, b)));
}
// lo16 = top16(d0), hi16 = top16(d1)
__device__ __forceinline__ unsigned pack_keys(float d0, float d1) {
    return __builtin_amdgcn_perm(__builtin_bit_cast(unsigned, d1),
                                 __builtin_bit_cast(unsigned, d0), 0x07060302u);
}

__global__ __launch_bounds__(512, 6)
void edgeconv_knn_kernel(const float* __restrict__ x,
                         const float* __restrict__ theta_w,
                         const float* __restrict__ theta_b,
                         const float* __restrict__ phi_w,
                         const float* __restrict__ phi_b,
                         float* __restrict__ out)
{
    __shared__ float    s_pl[3][NPTS];     // x,y,z planes, 48 KB contiguous
    __shared__ unsigned s_pool[8][64];     // 2 KB: per-wave survivor indices

    const int tid  = threadIdx.x;
    const int wv   = tid >> 6;
    const int lane = tid & 63;

    const int b  = blockIdx.x >> 7;        // 128 blocks per batch
    const int i0 = (blockIdx.x & 127) << 5;// 32 points per block (4 per wave)

    // lane == output channel e
    const float tw0 = theta_w[lane];
    const float tw1 = theta_w[64 + lane];
    const float tw2 = theta_w[128 + lane];
    const float tbv = theta_b[lane];
    const float pw0 = phi_w[lane];
    const float pw1 = phi_w[64 + lane];
    const float pw2 = phi_w[128 + lane];
    const float pbv = phi_b[lane];

    const float* xb = x + (size_t)b * NPTS * 3;
    for (int p = tid; p < NPTS; p += 512) {
        s_pl[0][p] = xb[p * 3 + 0];
        s_pl[1][p] = xb[p * 3 + 1];
        s_pl[2][p] = xb[p * 3 + 2];
    }
    __syncthreads();

    unsigned H = 0u;                       // carried u16 threshold

    for (int r = 0; r < 4; ++r) {
        const int i = i0 + wv * 4 + r;
        const float px = s_pl[0][i], py = s_pl[1][i], pz = s_pl[2][i];
        const float sqi = fmaf(pz, pz, fmaf(py, py, px * px));
        const f32x2 PX2 = {px, px}, PY2 = {py, py}, PZ2 = {pz, pz};
        const f32x2 SQI2 = {sqi, sqi};
        const f32x2 N2   = {-2.0f, -2.0f};
        const f32x2 Z02  = {0.0f, 0.0f};

        // ---- sweep: lane owns candidates j = 256*t + 4*lane + {0..3} ----
        // slot s=0..63 -> j = ((s>>2)<<8) + (lane<<2) + (s&3)
        unsigned pk[32];
        unsigned pmin = 0xFFFFFFFFu;
        #pragma unroll
        for (int t = 0; t < 16; ++t) {
            const int jb = (t << 8) + (lane << 2);
            const float4 QX = *(const float4*)&s_pl[0][jb];
            const float4 QY = *(const float4*)&s_pl[1][jb];
            const float4 QZ = *(const float4*)&s_pl[2][jb];
            const f32x2 X0 = {QX.x, QX.y}, X1 = {QX.z, QX.w};
            const f32x2 Y0 = {QY.x, QY.y}, Y1 = {QY.z, QY.w};
            const f32x2 Zc0 = {QZ.x, QZ.y}, Zc1 = {QZ.z, QZ.w};
            // sq_j with the identical chain: fma(z,z, fma(y,y, x*x))
            const f32x2 S0 = __builtin_elementwise_fma(Zc0, Zc0,
                             __builtin_elementwise_fma(Y0, Y0, X0 * X0));
            const f32x2 S1 = __builtin_elementwise_fma(Zc1, Zc1,
                             __builtin_elementwise_fma(Y1, Y1, X1 * X1));
            // dot with the identical chain: fma(pz,qz, fma(py,qy, px*qx))
            const f32x2 dt0 = __builtin_elementwise_fma(PZ2, Zc0,
                              __builtin_elementwise_fma(PY2, Y0, PX2 * X0));
            const f32x2 dt1 = __builtin_elementwise_fma(PZ2, Zc1,
                              __builtin_elementwise_fma(PY2, Y1, PX2 * X1));
            f32x2 d0 = __builtin_elementwise_fma(N2, dt0, SQI2 + S0);
            f32x2 d1 = __builtin_elementwise_fma(N2, dt1, SQI2 + S1);
            d0 = __builtin_elementwise_max(d0, Z02);
            d1 = __builtin_elementwise_max(d1, Z02);
            pk[2 * t]     = pack_keys(d0.x, d0.y);
            pk[2 * t + 1] = pack_keys(d1.x, d1.y);
            pmin = pk_min_u16(pmin, pk[2 * t]);
            pmin = pk_min_u16(pmin, pk[2 * t + 1]);
        }

        if (r == 0) {
            // bitonic sort of 64 lane-minima -> sampled starting threshold
            unsigned mn = min(pmin & 0xFFFFu, pmin >> 16);
            #pragma unroll
            for (int k = 2; k <= 64; k <<= 1) {
                #pragma unroll
                for (int jj = k >> 1; jj >= 1; jj >>= 1) {
                    const unsigned o = (unsigned)__shfl_xor((int)mn, jj, 64);
                    const bool wantmin = (((lane & k) == 0) == ((lane & jj) == 0));
                    const bool less = (mn < o);
                    if (less != wantmin) mn = o;
                }
            }
            H = (unsigned)__builtin_amdgcn_readlane((int)mn, 32);
        }
        // else: carry previous point's converged H as the seed (R6-proven)

        // ---- FUSED search + compaction: scan computes base == cnt_lt(H)
        //      while writing survivor indices (guard pos<64). Accept when
        //      base in [KNN,64]; else adjust H (gallop up / bisect down).
        unsigned L = 0u, U = 0x10000u, step = 0x80u;
        unsigned base;
        for (;;) {
            WFENCE();                        // prior pool consumers done
            base = 0;
            #pragma unroll
            for (int s = 0; s < 64; ++s) {
                const unsigned kk = (s & 1) ? (pk[s >> 1] >> 16)
                                            : (pk[s >> 1] & 0xFFFFu);
                const bool pred = kk < H;
                const unsigned long long bm = __ballot(pred);
                if (bm) {
                    if (pred) {
                        const unsigned pos = base + lane_prefix(bm);
                        if (pos < 64u)
                            s_pool[wv][pos] =
                                (unsigned)(((s >> 2) << 8) + (lane << 2) + (s & 3));
                    }
                    base += (unsigned)__popcll(bm);
                }
            }
            if (base >= KNN && base <= 64u) break;
            if (base < KNN) {                // H too low: raise
                L = H;
                if (U == 0x10000u) {         // still galloping
                    unsigned Hn = H + step;
                    if (Hn > 0xFFFFu) Hn = 0xFFFFu;
                    H = Hn; step <<= 1;
                } else {
                    H = L + ((U - L) >> 1);
                }
            } else {                         // base > 64: lower
                U = H;
                if (U - L <= 1u) break;      // fat-bin: accept (never in practice)
                H = L + ((U - L) >> 1);
            }
        }
        WFENCE();
        const unsigned m = base < 64u ? base : 64u;   // m >= 32 (mod fat-bin)

        // ---- exact fp32 keys for pool members (identical op chain) ----
        unsigned myk = 0xFFFFFFFFu;
        unsigned myj = 0u;                   // sentinel, never selected (m>=32)
        if ((unsigned)lane < m) {
            myj = s_pool[wv][lane];
            const float qx = s_pl[0][myj], qy = s_pl[1][myj], qz = s_pl[2][myj];
            const float sqj = fmaf(qz, qz, fmaf(qy, qy, qx * qx));
            const float dt  = fmaf(pz, qz, fmaf(py, qy, px * qx));
            float d = fmaf(-2.0f, dt, sqi + sqj);
            d = fmaxf(d, 0.0f);
            myk = __builtin_bit_cast(unsigned, d);
        }

        // ---- partial bitonic: 32-sorts + one merge -> bottom-32 unordered ----
        #pragma unroll
        for (int k = 2; k <= 32; k <<= 1) {
            #pragma unroll
            for (int jj = k >> 1; jj >= 1; jj >>= 1) {
                const unsigned ok = (unsigned)__shfl_xor((int)myk, jj, 64);
                const unsigned oj = (unsigned)__shfl_xor((int)myj, jj, 64);
                const bool wantmin = (((lane & k) == 0) == ((lane & jj) == 0));
                const bool less = (myk < ok) || (myk == ok && myj < oj);
                if (less != wantmin) { myk = ok; myj = oj; }
            }
        }
        {   // k=64, jj=32: lanes 0..31 <- the 32 smallest (unordered)
            const unsigned ok = (unsigned)__shfl_xor((int)myk, 32, 64);
            const unsigned oj = (unsigned)__shfl_xor((int)myj, 32, 64);
            const bool wantmin = ((lane & 32) == 0);
            const bool less = (myk < ok) || (myk == ok && myj < oj);
            if (less != wantmin) { myk = ok; myj = oj; }
        }

        // ---- epilogue: lane = channel e; max over the 32 selected ----
        float dx = 0.f, dy = 0.f, dz = 0.f;
        if (lane < KNN) {
            dx = s_pl[0][myj] - px; dy = s_pl[1][myj] - py; dz = s_pl[2][myj] - pz;
        }
        const float basev = tbv + pbv + fmaf(pw2, pz, fmaf(pw1, py, pw0 * px));
        float mx = -3.0e38f;
        #pragma unroll
        for (int t = 0; t < KNN; ++t) {
            const float ndx = __builtin_bit_cast(float, __builtin_amdgcn_readlane(__builtin_bit_cast(int, dx), t));
            const float ndy = __builtin_bit_cast(float, __builtin_amdgcn_readlane(__builtin_bit_cast(int, dy), t));
            const float ndz = __builtin_bit_cast(float, __builtin_amdgcn_readlane(__builtin_bit_cast(int, dz), t));
            const float proj = fmaf(tw2, ndz, fmaf(tw1, ndy, tw0 * ndx));
            mx = fmaxf(mx, proj);
        }
        out[(((size_t)b * NPTS + (size_t)i) << 6) + lane] = mx + basev;
    }
}

extern "C" void kernel_launch(void* const* d_in, const int* in_sizes, int n_in,
                              void* d_out, int out_size, void* d_ws, size_t ws_size,
                              hipStream_t stream) {
    const float* x  = (const float*)d_in[0];
    const float* tw = (const float*)d_in[1];
    const float* tb = (const float*)d_in[2];
    const float* pw = (const float*)d_in[3];
    const float* pb = (const float*)d_in[4];
    float* out = (float*)d_out;

    dim3 grid(8 * 128);   // 1024 blocks x 32 pts (R10-proven geometry)
    dim3 block(512);
    hipLaunchKernelGGL(edgeconv_knn_kernel, grid, block, 0, stream,
                       x, tw, tb, pw, pb, out);
}

// Round 14
// 162.852 us; speedup vs baseline: 1.3052x; 1.3052x over previous
//
#include <hip/hip_runtime.h>

// EdgeConv with KNN graph: B=8, N=4096, D=3, E=64, K=32.
// === R14: EXACT REVERT TO R10 (87.8 us, session best) ===
// Experiment ledger (falsified alternatives):
//  R11 (768-block exact-fit grid): occupancy 46->39, dur 127. Exact-fit
//      grids are fragile -- no backfill, uneven placement.
//  R12 (2048x16 grid): dur 100. Per-block staging (12KB global->LDS +
//      barrier) doubles; tail savings eaten. 1024x32 is the sweet spot.
//  R13 (fused probe+compaction): dur 160. Optimistic scan retries 2-4x
//      with LDS writes + fences; R10's factoring (cheap ballot probes,
//      ONE compaction) is correct.
// R10 structure:
//  - 3 planes x/y/z (48KB+2KB pool -> 3 blocks/CU, 24 waves/CU),
//  - in-sweep sq_j with BIT-IDENTICAL packed fmaf chain (self-dist == 0),
//  - u16 monotone-truncation keys pk[32] (superset pool, R6 proof),
//  - sampled threshold (minima bitonic at r=0), carried H for r>0,
//  - ballot probes, index-only compaction (ballot+mbcnt),
//  - exact-fp32 partial bitonic, lower-index tie-break == jax.lax.top_k,
//  - readlane epilogue.
// SPILL DISCIPLINE (R2/R3): every loop touching pk[] FULLY unrolled;
// (512,6) 85-VGPR budget, peak live ~75. TRIPWIRE: FETCH>4MB.

#define NPTS 4096
#define KNN  32

#define WFENCE() __asm__ volatile("s_waitcnt lgkmcnt(0)" ::: "memory")

typedef unsigned short u16x2 __attribute__((ext_vector_type(2)));
typedef float          f32x2 __attribute__((ext_vector_type(2)));

__device__ __forceinline__ unsigned lane_prefix(unsigned long long m) {
    return __builtin_amdgcn_mbcnt_hi((unsigned)(m >> 32),
           __builtin_amdgcn_mbcnt_lo((unsigned)m, 0u));
}
__device__ __forceinline__ unsigned pk_min_u16(unsigned a, unsigned b) {
    return __builtin_bit_cast(unsigned, __builtin_elementwise_min(
        __builtin_bit_cast(u16x2, a), __builtin_bit_cast(u16x2, b)));
}
// lo16 = top16(d0), hi16 = top16(d1)
__device__ __forceinline__ unsigned pack_keys(float d0, float d1) {
    return __builtin_amdgcn_perm(__builtin_bit_cast(unsigned, d1),
                                 __builtin_bit_cast(unsigned, d0), 0x07060302u);
}

__global__ __launch_bounds__(512, 6)
void edgeconv_knn_kernel(const float* __restrict__ x,
                         const float* __restrict__ theta_w,
                         const float* __restrict__ theta_b,
                         const float* __restrict__ phi_w,
                         const float* __restrict__ phi_b,
                         float* __restrict__ out)
{
    __shared__ float    s_x[NPTS];         // 16 KB per plane (48 KB total)
    __shared__ float    s_y[NPTS];
    __shared__ float    s_z[NPTS];
    __shared__ unsigned s_pool[8][64];     // 2 KB: per-wave survivor indices

    const int tid  = threadIdx.x;
    const int wv   = tid >> 6;
    const int lane = tid & 63;

    const int b  = blockIdx.x >> 7;        // 128 blocks per batch
    const int i0 = (blockIdx.x & 127) << 5;// 32 points per block (4 per wave)

    // lane == output channel e
    const float tw0 = theta_w[lane];
    const float tw1 = theta_w[64 + lane];
    const float tw2 = theta_w[128 + lane];
    const float tbv = theta_b[lane];
    const float pw0 = phi_w[lane];
    const float pw1 = phi_w[64 + lane];
    const float pw2 = phi_w[128 + lane];
    const float pbv = phi_b[lane];

    const float* xb = x + (size_t)b * NPTS * 3;
    for (int p = tid; p < NPTS; p += 512) {
        s_x[p] = xb[p * 3 + 0];
        s_y[p] = xb[p * 3 + 1];
        s_z[p] = xb[p * 3 + 2];
    }
    __syncthreads();

    unsigned H = 0u;                       // carried u16 threshold

    for (int r = 0; r < 4; ++r) {
        const int i = i0 + wv * 4 + r;
        const float px = s_x[i], py = s_y[i], pz = s_z[i];
        const float sqi = fmaf(pz, pz, fmaf(py, py, px * px));
        const f32x2 PX2 = {px, px}, PY2 = {py, py}, PZ2 = {pz, pz};
        const f32x2 SQI2 = {sqi, sqi};
        const f32x2 N2   = {-2.0f, -2.0f};
        const f32x2 Z02  = {0.0f, 0.0f};

        // ---- sweep: lane owns candidates j = 256*t + 4*lane + {0..3} ----
        // slot s=0..63 -> j = ((s>>2)<<8) + (lane<<2) + (s&3)
        unsigned pk[32];
        unsigned pmin = 0xFFFFFFFFu;
        #pragma unroll
        for (int t = 0; t < 16; ++t) {
            const int jb = (t << 8) + (lane << 2);
            const float4 QX = *(const float4*)&s_x[jb];
            const float4 QY = *(const float4*)&s_y[jb];
            const float4 QZ = *(const float4*)&s_z[jb];
            const f32x2 X0 = {QX.x, QX.y}, X1 = {QX.z, QX.w};
            const f32x2 Y0 = {QY.x, QY.y}, Y1 = {QY.z, QY.w};
            const f32x2 Zc0 = {QZ.x, QZ.y}, Zc1 = {QZ.z, QZ.w};
            // sq_j with the identical chain: fma(z,z, fma(y,y, x*x))
            const f32x2 S0 = __builtin_elementwise_fma(Zc0, Zc0,
                             __builtin_elementwise_fma(Y0, Y0, X0 * X0));
            const f32x2 S1 = __builtin_elementwise_fma(Zc1, Zc1,
                             __builtin_elementwise_fma(Y1, Y1, X1 * X1));
            // dot with the identical chain: fma(pz,qz, fma(py,qy, px*qx))
            const f32x2 dt0 = __builtin_elementwise_fma(PZ2, Zc0,
                              __builtin_elementwise_fma(PY2, Y0, PX2 * X0));
            const f32x2 dt1 = __builtin_elementwise_fma(PZ2, Zc1,
                              __builtin_elementwise_fma(PY2, Y1, PX2 * X1));
            f32x2 d0 = __builtin_elementwise_fma(N2, dt0, SQI2 + S0);
            f32x2 d1 = __builtin_elementwise_fma(N2, dt1, SQI2 + S1);
            d0 = __builtin_elementwise_max(d0, Z02);
            d1 = __builtin_elementwise_max(d1, Z02);
            pk[2 * t]     = pack_keys(d0.x, d0.y);
            pk[2 * t + 1] = pack_keys(d1.x, d1.y);
            pmin = pk_min_u16(pmin, pk[2 * t]);
            pmin = pk_min_u16(pmin, pk[2 * t + 1]);
        }

        if (r == 0) {
            // bitonic sort of 64 lane-minima -> sampled starting threshold
            unsigned mn = min(pmin & 0xFFFFu, pmin >> 16);
            #pragma unroll
            for (int k = 2; k <= 64; k <<= 1) {
                #pragma unroll
                for (int jj = k >> 1; jj >= 1; jj >>= 1) {
                    const unsigned o = (unsigned)__shfl_xor((int)mn, jj, 64);
                    const bool wantmin = (((lane & k) == 0) == ((lane & jj) == 0));
                    const bool less = (mn < o);
                    if (less != wantmin) mn = o;
                }
            }
            H = (unsigned)__builtin_amdgcn_readlane((int)mn, 32);
        }
        // else: carry previous point's converged H as the seed (R6-proven)

        // wave-uniform count of u16 keys strictly below T (ballot -> scalar)
        auto cnt_lt = [&](unsigned T) -> unsigned {
            unsigned c = 0;
            #pragma unroll
            for (int k2 = 0; k2 < 32; ++k2) {
                c += (unsigned)__popcll(__ballot((pk[k2] & 0xFFFFu) < T));
                c += (unsigned)__popcll(__ballot((pk[k2] >> 16)     < T));
            }
            return c;
        };

        // ---- threshold search in u16 key space ----
        unsigned L = 0u;
        unsigned c = cnt_lt(H);
        if (c < KNN) {                       // raise by octaves (exp LSB = 0x80)
            unsigned step = 0x80u;
            do {
                unsigned Hn = H + step;
                if (Hn > 0xFFFFu) Hn = 0xFFFFu;
                L = H; H = Hn; step <<= 1;
                c = cnt_lt(H);
            } while (c < KNN);
        }
        while (c > 64u && (H - L) > 1u) {
            const unsigned M  = L + ((H - L) >> 1);
            const unsigned cm = cnt_lt(M);
            if (cm >= KNN) { H = M; c = cm; } else { L = M; }
        }

        // ---- compaction: survivor indices only (ballot + mbcnt) ----
        WFENCE();                            // prior pool consumers done
        unsigned base = 0;
        #pragma unroll
        for (int s = 0; s < 64; ++s) {
            const unsigned kk = (s & 1) ? (pk[s >> 1] >> 16)
                                        : (pk[s >> 1] & 0xFFFFu);
            const bool pred = kk < H;
            const unsigned long long bm = __ballot(pred);
            if (bm) {
                if (pred) {
                    const unsigned pos = base + lane_prefix(bm);
                    if (pos < 64u)
                        s_pool[wv][pos] =
                            (unsigned)(((s >> 2) << 8) + (lane << 2) + (s & 3));
                }
                base += (unsigned)__popcll(bm);
            }
        }
        WFENCE();
        const unsigned m = base < 64u ? base : 64u;   // m >= 32 guaranteed

        // ---- exact fp32 keys for pool members (identical op chain) ----
        unsigned myk = 0xFFFFFFFFu;
        unsigned myj = 0u;                   // sentinel, never selected (m>=32)
        if ((unsigned)lane < m) {
            myj = s_pool[wv][lane];
            const float qx = s_x[myj], qy = s_y[myj], qz = s_z[myj];
            const float sqj = fmaf(qz, qz, fmaf(qy, qy, qx * qx));
            const float dt  = fmaf(pz, qz, fmaf(py, qy, px * qx));
            float d = fmaf(-2.0f, dt, sqi + sqj);
            d = fmaxf(d, 0.0f);
            myk = __builtin_bit_cast(unsigned, d);
        }

        // ---- partial bitonic: 32-sorts + one merge -> bottom-32 unordered ----
        #pragma unroll
        for (int k = 2; k <= 32; k <<= 1) {
            #pragma unroll
            for (int jj = k >> 1; jj >= 1; jj >>= 1) {
                const unsigned ok = (unsigned)__shfl_xor((int)myk, jj, 64);
                const unsigned oj = (unsigned)__shfl_xor((int)myj, jj, 64);
                const bool wantmin = (((lane & k) == 0) == ((lane & jj) == 0));
                const bool less = (myk < ok) || (myk == ok && myj < oj);
                if (less != wantmin) { myk = ok; myj = oj; }
            }
        }
        {   // k=64, jj=32: lanes 0..31 <- the 32 smallest (unordered)
            const unsigned ok = (unsigned)__shfl_xor((int)myk, 32, 64);
            const unsigned oj = (unsigned)__shfl_xor((int)myj, 32, 64);
            const bool wantmin = ((lane & 32) == 0);
            const bool less = (myk < ok) || (myk == ok && myj < oj);
            if (less != wantmin) { myk = ok; myj = oj; }
        }

        // ---- epilogue: lane = channel e; max over the 32 selected ----
        float dx = 0.f, dy = 0.f, dz = 0.f;
        if (lane < KNN) {
            dx = s_x[myj] - px; dy = s_y[myj] - py; dz = s_z[myj] - pz;
        }
        const float basev = tbv + pbv + fmaf(pw2, pz, fmaf(pw1, py, pw0 * px));
        float mx = -3.0e38f;
        #pragma unroll
        for (int t = 0; t < KNN; ++t) {
            const float ndx = __builtin_bit_cast(float, __builtin_amdgcn_readlane(__builtin_bit_cast(int, dx), t));
            const float ndy = __builtin_bit_cast(float, __builtin_amdgcn_readlane(__builtin_bit_cast(int, dy), t));
            const float ndz = __builtin_bit_cast(float, __builtin_amdgcn_readlane(__builtin_bit_cast(int, dz), t));
            const float proj = fmaf(tw2, ndz, fmaf(tw1, ndy, tw0 * ndx));
            mx = fmaxf(mx, proj);
        }
        out[(((size_t)b * NPTS + (size_t)i) << 6) + lane] = mx + basev;
    }
}

extern "C" void kernel_launch(void* const* d_in, const int* in_sizes, int n_in,
                              void* d_out, int out_size, void* d_ws, size_t ws_size,
                              hipStream_t stream) {
    const float* x  = (const float*)d_in[0];
    const float* tw = (const float*)d_in[1];
    const float* tb = (const float*)d_in[2];
    const float* pw = (const float*)d_in[3];
    const float* pb = (const float*)d_in[4];
    float* out = (float*)d_out;

    dim3 grid(8 * 128);   // 1024 blocks x 32 pts (R10-proven geometry)
    dim3 block(512);
    hipLaunchKernelGGL(edgeconv_knn_kernel, grid, block, 0, stream,
                       x, tw, tb, pw, pb, out);
}

// Round 15
// 138.663 us; speedup vs baseline: 1.5329x; 1.1744x over previous
//
#include <hip/hip_runtime.h>

// EdgeConv with KNN graph: B=8, N=4096, D=3, E=64, K=32.
// === R15: TRUE verbatim revert to the Round-10 kernel (87.8 us best) ===
// R14 post-mortem: the "exact revert" carried H across points (minima sort
// only at r=0). With random input, consecutive indices are spatially
// unrelated -> carried H misses -> 8-14 SERIAL ballot probes per point
// (vs ~2), dur 126 us. Fresh per-point sampled threshold is mandatory:
//   R8 fresh=93.6 | R10 fresh=87.8 | R11 carried=127 | R12 carried=100 |
//   R14 carried=126.  Carried-H is FALSIFIED (not grid geometry alone).
// Structure (all proven):
//  - 3 planes x/y/z (48KB+2KB pool -> 3 blocks/CU, 24 waves/CU),
//  - in-sweep sq_j with BIT-IDENTICAL packed fmaf chain (self-dist == 0),
//  - u16 monotone-truncation keys pk[32] (superset pool, R6 proof),
//  - PER-POINT sampled threshold: bitonic sort of 64 lane-minima,
//    H = 33rd smallest lane-min (readlane 32),
//  - ballot probes (gallop/bisect), ONE index-only compaction,
//  - exact-fp32 partial bitonic, lower-index tie-break == jax.lax.top_k,
//  - readlane epilogue; grid 1024 x 32 pts (R10-proven geometry).
// SPILL DISCIPLINE (R2/R3): every loop touching pk[] FULLY unrolled;
// (512,6) 85-VGPR budget, peak live ~75. TRIPWIRE: FETCH>4MB.

#define NPTS 4096
#define KNN  32

#define WFENCE() __asm__ volatile("s_waitcnt lgkmcnt(0)" ::: "memory")

typedef unsigned short u16x2 __attribute__((ext_vector_type(2)));
typedef float          f32x2 __attribute__((ext_vector_type(2)));

__device__ __forceinline__ unsigned lane_prefix(unsigned long long m) {
    return __builtin_amdgcn_mbcnt_hi((unsigned)(m >> 32),
           __builtin_amdgcn_mbcnt_lo((unsigned)m, 0u));
}
__device__ __forceinline__ unsigned pk_min_u16(unsigned a, unsigned b) {
    return __builtin_bit_cast(unsigned, __builtin_elementwise_min(
        __builtin_bit_cast(u16x2, a), __builtin_bit_cast(u16x2, b)));
}
// lo16 = top16(d0), hi16 = top16(d1)
__device__ __forceinline__ unsigned pack_keys(float d0, float d1) {
    return __builtin_amdgcn_perm(__builtin_bit_cast(unsigned, d1),
                                 __builtin_bit_cast(unsigned, d0), 0x07060302u);
}

__global__ __launch_bounds__(512, 6)
void edgeconv_knn_kernel(const float* __restrict__ x,
                         const float* __restrict__ theta_w,
                         const float* __restrict__ theta_b,
                         const float* __restrict__ phi_w,
                         const float* __restrict__ phi_b,
                         float* __restrict__ out)
{
    __shared__ float    s_x[NPTS];         // 16 KB per plane (48 KB total)
    __shared__ float    s_y[NPTS];
    __shared__ float    s_z[NPTS];
    __shared__ unsigned s_pool[8][64];     // 2 KB: per-wave survivor indices

    const int tid  = threadIdx.x;
    const int wv   = tid >> 6;
    const int lane = tid & 63;

    const int b  = blockIdx.x >> 7;        // 128 blocks per batch
    const int i0 = (blockIdx.x & 127) << 5;// 32 points per block (4 per wave)

    // lane == output channel e
    const float tw0 = theta_w[lane];
    const float tw1 = theta_w[64 + lane];
    const float tw2 = theta_w[128 + lane];
    const float tbv = theta_b[lane];
    const float pw0 = phi_w[lane];
    const float pw1 = phi_w[64 + lane];
    const float pw2 = phi_w[128 + lane];
    const float pbv = phi_b[lane];

    const float* xb = x + (size_t)b * NPTS * 3;
    for (int p = tid; p < NPTS; p += 512) {
        s_x[p] = xb[p * 3 + 0];
        s_y[p] = xb[p * 3 + 1];
        s_z[p] = xb[p * 3 + 2];
    }
    __syncthreads();

    for (int r = 0; r < 4; ++r) {
        const int i = i0 + wv * 4 + r;
        const float px = s_x[i], py = s_y[i], pz = s_z[i];
        const float sqi = fmaf(pz, pz, fmaf(py, py, px * px));
        const f32x2 PX2 = {px, px}, PY2 = {py, py}, PZ2 = {pz, pz};
        const f32x2 SQI2 = {sqi, sqi};
        const f32x2 N2   = {-2.0f, -2.0f};
        const f32x2 Z02  = {0.0f, 0.0f};

        // ---- sweep: lane owns candidates j = 256*t + 4*lane + {0..3} ----
        // slot s=0..63 -> j = ((s>>2)<<8) + (lane<<2) + (s&3)
        unsigned pk[32];
        unsigned pmin = 0xFFFFFFFFu;
        #pragma unroll
        for (int t = 0; t < 16; ++t) {
            const int jb = (t << 8) + (lane << 2);
            const float4 QX = *(const float4*)&s_x[jb];
            const float4 QY = *(const float4*)&s_y[jb];
            const float4 QZ = *(const float4*)&s_z[jb];
            const f32x2 X0 = {QX.x, QX.y}, X1 = {QX.z, QX.w};
            const f32x2 Y0 = {QY.x, QY.y}, Y1 = {QY.z, QY.w};
            const f32x2 Zc0 = {QZ.x, QZ.y}, Zc1 = {QZ.z, QZ.w};
            // sq_j with the identical chain: fma(z,z, fma(y,y, x*x))
            const f32x2 S0 = __builtin_elementwise_fma(Zc0, Zc0,
                             __builtin_elementwise_fma(Y0, Y0, X0 * X0));
            const f32x2 S1 = __builtin_elementwise_fma(Zc1, Zc1,
                             __builtin_elementwise_fma(Y1, Y1, X1 * X1));
            // dot with the identical chain: fma(pz,qz, fma(py,qy, px*qx))
            const f32x2 dt0 = __builtin_elementwise_fma(PZ2, Zc0,
                              __builtin_elementwise_fma(PY2, Y0, PX2 * X0));
            const f32x2 dt1 = __builtin_elementwise_fma(PZ2, Zc1,
                              __builtin_elementwise_fma(PY2, Y1, PX2 * X1));
            f32x2 d0 = __builtin_elementwise_fma(N2, dt0, SQI2 + S0);
            f32x2 d1 = __builtin_elementwise_fma(N2, dt1, SQI2 + S1);
            d0 = __builtin_elementwise_max(d0, Z02);
            d1 = __builtin_elementwise_max(d1, Z02);
            pk[2 * t]     = pack_keys(d0.x, d0.y);
            pk[2 * t + 1] = pack_keys(d1.x, d1.y);
            pmin = pk_min_u16(pmin, pk[2 * t]);
            pmin = pk_min_u16(pmin, pk[2 * t + 1]);
        }
        unsigned mn = min(pmin & 0xFFFFu, pmin >> 16);   // per-lane min (u16)

        // ---- PER-POINT bitonic sort of 64 lane-minima -> sampled threshold
        #pragma unroll
        for (int k = 2; k <= 64; k <<= 1) {
            #pragma unroll
            for (int jj = k >> 1; jj >= 1; jj >>= 1) {
                const unsigned o = (unsigned)__shfl_xor((int)mn, jj, 64);
                const bool wantmin = (((lane & k) == 0) == ((lane & jj) == 0));
                const bool less = (mn < o);
                if (less != wantmin) mn = o;
            }
        }
        unsigned H = (unsigned)__builtin_amdgcn_readlane((int)mn, 32);

        // wave-uniform count of u16 keys strictly below T (ballot -> scalar)
        auto cnt_lt = [&](unsigned T) -> unsigned {
            unsigned c = 0;
            #pragma unroll
            for (int k2 = 0; k2 < 32; ++k2) {
                c += (unsigned)__popcll(__ballot((pk[k2] & 0xFFFFu) < T));
                c += (unsigned)__popcll(__ballot((pk[k2] >> 16)     < T));
            }
            return c;
        };

        // ---- threshold search in u16 key space ----
        unsigned L = 0u;
        unsigned c = cnt_lt(H);
        if (c < KNN) {                       // raise by octaves (exp LSB = 0x80)
            unsigned step = 0x80u;
            do {
                unsigned Hn = H + step;
                if (Hn > 0xFFFFu) Hn = 0xFFFFu;
                L = H; H = Hn; step <<= 1;
                c = cnt_lt(H);
            } while (c < KNN);
        }
        while (c > 64u && (H - L) > 1u) {
            const unsigned M  = L + ((H - L) >> 1);
            const unsigned cm = cnt_lt(M);
            if (cm >= KNN) { H = M; c = cm; } else { L = M; }
        }

        // ---- compaction: survivor indices only (ballot + mbcnt) ----
        WFENCE();                            // prior pool consumers done
        unsigned base = 0;
        #pragma unroll
        for (int s = 0; s < 64; ++s) {
            const unsigned kk = (s & 1) ? (pk[s >> 1] >> 16)
                                        : (pk[s >> 1] & 0xFFFFu);
            const bool pred = kk < H;
            const unsigned long long bm = __ballot(pred);
            if (bm) {
                if (pred) {
                    const unsigned pos = base + lane_prefix(bm);
                    if (pos < 64u)
                        s_pool[wv][pos] =
                            (unsigned)(((s >> 2) << 8) + (lane << 2) + (s & 3));
                }
                base += (unsigned)__popcll(bm);
            }
        }
        WFENCE();
        const unsigned m = base < 64u ? base : 64u;   // m >= 32 guaranteed

        // ---- exact fp32 keys for pool members (identical op chain) ----
        unsigned myk = 0xFFFFFFFFu;
        unsigned myj = 0u;                   // sentinel, never selected (m>=32)
        if ((unsigned)lane < m) {
            myj = s_pool[wv][lane];
            const float qx = s_x[myj], qy = s_y[myj], qz = s_z[myj];
            const float sqj = fmaf(qz, qz, fmaf(qy, qy, qx * qx));
            const float dt  = fmaf(pz, qz, fmaf(py, qy, px * qx));
            float d = fmaf(-2.0f, dt, sqi + sqj);
            d = fmaxf(d, 0.0f);
            myk = __builtin_bit_cast(unsigned, d);
        }

        // ---- partial bitonic: 32-sorts + one merge -> bottom-32 unordered ----
        #pragma unroll
        for (int k = 2; k <= 32; k <<= 1) {
            #pragma unroll
            for (int jj = k >> 1; jj >= 1; jj >>= 1) {
                const unsigned ok = (unsigned)__shfl_xor((int)myk, jj, 64);
                const unsigned oj = (unsigned)__shfl_xor((int)myj, jj, 64);
                const bool wantmin = (((lane & k) == 0) == ((lane & jj) == 0));
                const bool less = (myk < ok) || (myk == ok && myj < oj);
                if (less != wantmin) { myk = ok; myj = oj; }
            }
        }
        {   // k=64, jj=32: lanes 0..31 <- the 32 smallest (unordered)
            const unsigned ok = (unsigned)__shfl_xor((int)myk, 32, 64);
            const unsigned oj = (unsigned)__shfl_xor((int)myj, 32, 64);
            const bool wantmin = ((lane & 32) == 0);
            const bool less = (myk < ok) || (myk == ok && myj < oj);
            if (less != wantmin) { myk = ok; myj = oj; }
        }

        // ---- epilogue: lane = channel e; max over the 32 selected ----
        float dx = 0.f, dy = 0.f, dz = 0.f;
        if (lane < KNN) {
            dx = s_x[myj] - px; dy = s_y[myj] - py; dz = s_z[myj] - pz;
        }
        const float basev = tbv + pbv + fmaf(pw2, pz, fmaf(pw1, py, pw0 * px));
        float mx = -3.0e38f;
        #pragma unroll
        for (int t = 0; t < KNN; ++t) {
            const float ndx = __builtin_bit_cast(float, __builtin_amdgcn_readlane(__builtin_bit_cast(int, dx), t));
            const float ndy = __builtin_bit_cast(float, __builtin_amdgcn_readlane(__builtin_bit_cast(int, dy), t));
            const float ndz = __builtin_bit_cast(float, __builtin_amdgcn_readlane(__builtin_bit_cast(int, dz), t));
            const float proj = fmaf(tw2, ndz, fmaf(tw1, ndy, tw0 * ndx));
            mx = fmaxf(mx, proj);
        }
        out[(((size_t)b * NPTS + (size_t)i) << 6) + lane] = mx + basev;
    }
}

extern "C" void kernel_launch(void* const* d_in, const int* in_sizes, int n_in,
                              void* d_out, int out_size, void* d_ws, size_t ws_size,
                              hipStream_t stream) {
    const float* x  = (const float*)d_in[0];
    const float* tw = (const float*)d_in[1];
    const float* tb = (const float*)d_in[2];
    const float* pw = (const float*)d_in[3];
    const float* pb = (const float*)d_in[4];
    float* out = (float*)d_out;

    dim3 grid(8 * 128);   // 1024 blocks x 32 pts (R10-proven geometry)
    dim3 block(512);
    hipLaunchKernelGGL(edgeconv_knn_kernel, grid, block, 0, stream,
                       x, tw, tb, pw, pb, out);
}

// Round 16
// 135.384 us; speedup vs baseline: 1.5700x; 1.0242x over previous
//
#include <hip/hip_runtime.h>

// EdgeConv with KNN graph: B=8, N=4096, D=3, E=64, K=32.
// === R16: R15 body (88.4 us verified) + 2048x16 grid, FRESH per-point H ===
// R15 post-mortem: R11/R12 grid experiments were CONFOUNDED by carried-H
// (R14 measured carried-H at ~+40% on affected points). Correcting R12's
// 100 us for its half-carried points projects a fresh-H 2048x16 grid at
// ~83-87 us. Occupancy counter (46% = ~15 waves avg vs 24 resident) shows
// the 1024-block tail is real: 2 rounds, 2nd only 1/3 full (67% slot util);
// 2048 blocks -> 3 rounds at 89% util, for ~2x (small) staging cost.
// Single variable vs R15: grid geometry. Kernel body unchanged:
//  - 3 planes x/y/z (48KB+2KB pool -> 3 blocks/CU, 24 waves/CU),
//  - in-sweep sq_j with BIT-IDENTICAL packed fmaf chain (self-dist == 0),
//  - u16 monotone-truncation keys pk[32] (superset pool, R6 proof),
//  - PER-POINT sampled threshold (bitonic of 64 lane-minima, readlane 32),
//  - ballot probes (gallop/bisect), ONE index-only compaction,
//  - exact-fp32 partial bitonic, lower-index tie-break == jax.lax.top_k,
//  - readlane epilogue.
// SPILL DISCIPLINE (R2/R3): every loop touching pk[] FULLY unrolled;
// (512,6) 85-VGPR budget. TRIPWIRE: FETCH>6MB.

#define NPTS 4096
#define KNN  32

#define WFENCE() __asm__ volatile("s_waitcnt lgkmcnt(0)" ::: "memory")

typedef unsigned short u16x2 __attribute__((ext_vector_type(2)));
typedef float          f32x2 __attribute__((ext_vector_type(2)));

__device__ __forceinline__ unsigned lane_prefix(unsigned long long m) {
    return __builtin_amdgcn_mbcnt_hi((unsigned)(m >> 32),
           __builtin_amdgcn_mbcnt_lo((unsigned)m, 0u));
}
__device__ __forceinline__ unsigned pk_min_u16(unsigned a, unsigned b) {
    return __builtin_bit_cast(unsigned, __builtin_elementwise_min(
        __builtin_bit_cast(u16x2, a), __builtin_bit_cast(u16x2, b)));
}
// lo16 = top16(d0), hi16 = top16(d1)
__device__ __forceinline__ unsigned pack_keys(float d0, float d1) {
    return __builtin_amdgcn_perm(__builtin_bit_cast(unsigned, d1),
                                 __builtin_bit_cast(unsigned, d0), 0x07060302u);
}

__global__ __launch_bounds__(512, 6)
void edgeconv_knn_kernel(const float* __restrict__ x,
                         const float* __restrict__ theta_w,
                         const float* __restrict__ theta_b,
                         const float* __restrict__ phi_w,
                         const float* __restrict__ phi_b,
                         float* __restrict__ out)
{
    __shared__ float    s_x[NPTS];         // 16 KB per plane (48 KB total)
    __shared__ float    s_y[NPTS];
    __shared__ float    s_z[NPTS];
    __shared__ unsigned s_pool[8][64];     // 2 KB: per-wave survivor indices

    const int tid  = threadIdx.x;
    const int wv   = tid >> 6;
    const int lane = tid & 63;

    const int b  = blockIdx.x >> 8;        // 256 blocks per batch
    const int i0 = (blockIdx.x & 255) << 4;// 16 points per block (2 per wave)

    // lane == output channel e
    const float tw0 = theta_w[lane];
    const float tw1 = theta_w[64 + lane];
    const float tw2 = theta_w[128 + lane];
    const float tbv = theta_b[lane];
    const float pw0 = phi_w[lane];
    const float pw1 = phi_w[64 + lane];
    const float pw2 = phi_w[128 + lane];
    const float pbv = phi_b[lane];

    const float* xb = x + (size_t)b * NPTS * 3;
    for (int p = tid; p < NPTS; p += 512) {
        s_x[p] = xb[p * 3 + 0];
        s_y[p] = xb[p * 3 + 1];
        s_z[p] = xb[p * 3 + 2];
    }
    __syncthreads();

    for (int r = 0; r < 2; ++r) {
        const int i = i0 + wv * 2 + r;
        const float px = s_x[i], py = s_y[i], pz = s_z[i];
        const float sqi = fmaf(pz, pz, fmaf(py, py, px * px));
        const f32x2 PX2 = {px, px}, PY2 = {py, py}, PZ2 = {pz, pz};
        const f32x2 SQI2 = {sqi, sqi};
        const f32x2 N2   = {-2.0f, -2.0f};
        const f32x2 Z02  = {0.0f, 0.0f};

        // ---- sweep: lane owns candidates j = 256*t + 4*lane + {0..3} ----
        // slot s=0..63 -> j = ((s>>2)<<8) + (lane<<2) + (s&3)
        unsigned pk[32];
        unsigned pmin = 0xFFFFFFFFu;
        #pragma unroll
        for (int t = 0; t < 16; ++t) {
            const int jb = (t << 8) + (lane << 2);
            const float4 QX = *(const float4*)&s_x[jb];
            const float4 QY = *(const float4*)&s_y[jb];
            const float4 QZ = *(const float4*)&s_z[jb];
            const f32x2 X0 = {QX.x, QX.y}, X1 = {QX.z, QX.w};
            const f32x2 Y0 = {QY.x, QY.y}, Y1 = {QY.z, QY.w};
            const f32x2 Zc0 = {QZ.x, QZ.y}, Zc1 = {QZ.z, QZ.w};
            // sq_j with the identical chain: fma(z,z, fma(y,y, x*x))
            const f32x2 S0 = __builtin_elementwise_fma(Zc0, Zc0,
                             __builtin_elementwise_fma(Y0, Y0, X0 * X0));
            const f32x2 S1 = __builtin_elementwise_fma(Zc1, Zc1,
                             __builtin_elementwise_fma(Y1, Y1, X1 * X1));
            // dot with the identical chain: fma(pz,qz, fma(py,qy, px*qx))
            const f32x2 dt0 = __builtin_elementwise_fma(PZ2, Zc0,
                              __builtin_elementwise_fma(PY2, Y0, PX2 * X0));
            const f32x2 dt1 = __builtin_elementwise_fma(PZ2, Zc1,
                              __builtin_elementwise_fma(PY2, Y1, PX2 * X1));
            f32x2 d0 = __builtin_elementwise_fma(N2, dt0, SQI2 + S0);
            f32x2 d1 = __builtin_elementwise_fma(N2, dt1, SQI2 + S1);
            d0 = __builtin_elementwise_max(d0, Z02);
            d1 = __builtin_elementwise_max(d1, Z02);
            pk[2 * t]     = pack_keys(d0.x, d0.y);
            pk[2 * t + 1] = pack_keys(d1.x, d1.y);
            pmin = pk_min_u16(pmin, pk[2 * t]);
            pmin = pk_min_u16(pmin, pk[2 * t + 1]);
        }
        unsigned mn = min(pmin & 0xFFFFu, pmin >> 16);   // per-lane min (u16)

        // ---- PER-POINT bitonic sort of 64 lane-minima -> sampled threshold
        #pragma unroll
        for (int k = 2; k <= 64; k <<= 1) {
            #pragma unroll
            for (int jj = k >> 1; jj >= 1; jj >>= 1) {
                const unsigned o = (unsigned)__shfl_xor((int)mn, jj, 64);
                const bool wantmin = (((lane & k) == 0) == ((lane & jj) == 0));
                const bool less = (mn < o);
                if (less != wantmin) mn = o;
            }
        }
        unsigned H = (unsigned)__builtin_amdgcn_readlane((int)mn, 32);

        // wave-uniform count of u16 keys strictly below T (ballot -> scalar)
        auto cnt_lt = [&](unsigned T) -> unsigned {
            unsigned c = 0;
            #pragma unroll
            for (int k2 = 0; k2 < 32; ++k2) {
                c += (unsigned)__popcll(__ballot((pk[k2] & 0xFFFFu) < T));
                c += (unsigned)__popcll(__ballot((pk[k2] >> 16)     < T));
            }
            return c;
        };

        // ---- threshold search in u16 key space ----
        unsigned L = 0u;
        unsigned c = cnt_lt(H);
        if (c < KNN) {                       // raise by octaves (exp LSB = 0x80)
            unsigned step = 0x80u;
            do {
                unsigned Hn = H + step;
                if (Hn > 0xFFFFu) Hn = 0xFFFFu;
                L = H; H = Hn; step <<= 1;
                c = cnt_lt(H);
            } while (c < KNN);
        }
        while (c > 64u && (H - L) > 1u) {
            const unsigned M  = L + ((H - L) >> 1);
            const unsigned cm = cnt_lt(M);
            if (cm >= KNN) { H = M; c = cm; } else { L = M; }
        }

        // ---- compaction: survivor indices only (ballot + mbcnt) ----
        WFENCE();                            // prior pool consumers done
        unsigned base = 0;
        #pragma unroll
        for (int s = 0; s < 64; ++s) {
            const unsigned kk = (s & 1) ? (pk[s >> 1] >> 16)
                                        : (pk[s >> 1] & 0xFFFFu);
            const bool pred = kk < H;
            const unsigned long long bm = __ballot(pred);
            if (bm) {
                if (pred) {
                    const unsigned pos = base + lane_prefix(bm);
                    if (pos < 64u)
                        s_pool[wv][pos] =
                            (unsigned)(((s >> 2) << 8) + (lane << 2) + (s & 3));
                }
                base += (unsigned)__popcll(bm);
            }
        }
        WFENCE();
        const unsigned m = base < 64u ? base : 64u;   // m >= 32 guaranteed

        // ---- exact fp32 keys for pool members (identical op chain) ----
        unsigned myk = 0xFFFFFFFFu;
        unsigned myj = 0u;                   // sentinel, never selected (m>=32)
        if ((unsigned)lane < m) {
            myj = s_pool[wv][lane];
            const float qx = s_x[myj], qy = s_y[myj], qz = s_z[myj];
            const float sqj = fmaf(qz, qz, fmaf(qy, qy, qx * qx));
            const float dt  = fmaf(pz, qz, fmaf(py, qy, px * qx));
            float d = fmaf(-2.0f, dt, sqi + sqj);
            d = fmaxf(d, 0.0f);
            myk = __builtin_bit_cast(unsigned, d);
        }

        // ---- partial bitonic: 32-sorts + one merge -> bottom-32 unordered ----
        #pragma unroll
        for (int k = 2; k <= 32; k <<= 1) {
            #pragma unroll
            for (int jj = k >> 1; jj >= 1; jj >>= 1) {
                const unsigned ok = (unsigned)__shfl_xor((int)myk, jj, 64);
                const unsigned oj = (unsigned)__shfl_xor((int)myj, jj, 64);
                const bool wantmin = (((lane & k) == 0) == ((lane & jj) == 0));
                const bool less = (myk < ok) || (myk == ok && myj < oj);
                if (less != wantmin) { myk = ok; myj = oj; }
            }
        }
        {   // k=64, jj=32: lanes 0..31 <- the 32 smallest (unordered)
            const unsigned ok = (unsigned)__shfl_xor((int)myk, 32, 64);
            const unsigned oj = (unsigned)__shfl_xor((int)myj, 32, 64);
            const bool wantmin = ((lane & 32) == 0);
            const bool less = (myk < ok) || (myk == ok && myj < oj);
            if (less != wantmin) { myk = ok; myj = oj; }
        }

        // ---- epilogue: lane = channel e; max over the 32 selected ----
        float dx = 0.f, dy = 0.f, dz = 0.f;
        if (lane < KNN) {
            dx = s_x[myj] - px; dy = s_y[myj] - py; dz = s_z[myj] - pz;
        }
        const float basev = tbv + pbv + fmaf(pw2, pz, fmaf(pw1, py, pw0 * px));
        float mx = -3.0e38f;
        #pragma unroll
        for (int t = 0; t < KNN; ++t) {
            const float ndx = __builtin_bit_cast(float, __builtin_amdgcn_readlane(__builtin_bit_cast(int, dx), t));
            const float ndy = __builtin_bit_cast(float, __builtin_amdgcn_readlane(__builtin_bit_cast(int, dy), t));
            const float ndz = __builtin_bit_cast(float, __builtin_amdgcn_readlane(__builtin_bit_cast(int, dz), t));
            const float proj = fmaf(tw2, ndz, fmaf(tw1, ndy, tw0 * ndx));
            mx = fmaxf(mx, proj);
        }
        out[(((size_t)b * NPTS + (size_t)i) << 6) + lane] = mx + basev;
    }
}

extern "C" void kernel_launch(void* const* d_in, const int* in_sizes, int n_in,
                              void* d_out, int out_size, void* d_ws, size_t ws_size,
                              hipStream_t stream) {
    const float* x  = (const float*)d_in[0];
    const float* tw = (const float*)d_in[1];
    const float* tb = (const float*)d_in[2];
    const float* pw = (const float*)d_in[3];
    const float* pb = (const float*)d_in[4];
    float* out = (float*)d_out;

    dim3 grid(8 * 256);   // 2048 blocks x 16 pts, fresh per-point H
    dim3 block(512);
    hipLaunchKernelGGL(edgeconv_knn_kernel, grid, block, 0, stream,
                       x, tw, tb, pw, pb, out);
}